// Round 3
// baseline (1034.132 us; speedup 1.0000x reference)
//
#include <hip/hip_runtime.h>
#include <hip/hip_bf16.h>
#include <cstdint>

#define M_DIM 8192
#define K_DIM 4096
#define N_DIM 11008
#define NGROUPS 32

typedef __attribute__((ext_vector_type(4))) float f32x4;
typedef __attribute__((ext_vector_type(8))) __bf16 bf16x8;

__device__ __forceinline__ unsigned int f2bf(float f) {
  unsigned int u = __builtin_bit_cast(unsigned int, f);
  return (u + 0x7FFFu + ((u >> 16) & 1u)) >> 16;   // RNE f32->bf16
}
__device__ __forceinline__ unsigned int pk2(float lo, float hi) {
  return f2bf(lo) | (f2bf(hi) << 16);
}

// ---------------- prepass: A fp32 -> bf16 ----------------
__global__ __launch_bounds__(256) void cvtA_kernel(const float* __restrict__ in,
                                                   unsigned short* __restrict__ outA) {
  size_t g = (size_t)blockIdx.x * 256 + threadIdx.x;
  size_t base = g * 8;
  const float4* p = (const float4*)(in + base);
  float4 a = p[0], b = p[1];
  uint4 v;
  v.x = pk2(a.x, a.y); v.y = pk2(a.z, a.w);
  v.z = pk2(b.x, b.y); v.w = pk2(b.z, b.w);
  *(uint4*)(outA + base) = v;
}

// ---------------- prepass: W int codes * scale -> bf16 ----------------
__global__ __launch_bounds__(256) void dequantW_kernel(const int* __restrict__ w,
                                                       const float* __restrict__ sc,
                                                       unsigned short* __restrict__ outB) {
  size_t g = (size_t)blockIdx.x * 256 + threadIdx.x;
  size_t base = g * 8;
  unsigned n = (unsigned)(base >> 12);
  unsigned k = (unsigned)base & 4095u;
  float s = sc[n * NGROUPS + (k >> 7)];
  const int4* p = (const int4*)(w + base);
  int4 c0 = p[0], c1 = p[1];
  uint4 v;
  v.x = pk2((float)c0.x * s, (float)c0.y * s);
  v.y = pk2((float)c0.z * s, (float)c0.w * s);
  v.z = pk2((float)c1.x * s, (float)c1.y * s);
  v.w = pk2((float)c1.z * s, (float)c1.w * s);
  *(uint4*)(outB + base) = v;
}

__device__ __forceinline__ void gload16(const void* g, void* l) {
  __builtin_amdgcn_global_load_lds((const __attribute__((address_space(1))) void*)g,
                                   (__attribute__((address_space(3))) void*)l,
                                   16, 0, 0);
}

// ============ 256x256, BK=32, 4-deep pipelined GEMM (T1..T5) ============
#define BM 256
#define BN 256
#define BK 32
#define NKT (K_DIM / BK)          /* 128 */
#define TILES_M (M_DIM / BM)      /* 32 */
#define TILES_N (N_DIM / BN)      /* 43 */
#define NB2 (TILES_M * TILES_N)   /* 1376, %8==0 */
#define TSZ (BM * BK)             /* elems per buffer (16 KiB) */

#define VMCNT_(n) asm volatile("s_waitcnt vmcnt(" #n ")" ::: "memory")
#define VMCNT(n) VMCNT_(n)
#define BAR() __builtin_amdgcn_s_barrier()

__global__ __launch_bounds__(512, 2) void gemm8_kernel(
    const unsigned short* __restrict__ A,   // bf16 [M][K]
    const unsigned short* __restrict__ B,   // bf16 [N][K]
    const float* __restrict__ bias,
    float* __restrict__ out) {
  __shared__ unsigned short sA[4][TSZ];   // 64 KiB
  __shared__ unsigned short sB[4][TSZ];   // 64 KiB

  const int t = threadIdx.x;
  const int bid = blockIdx.x;
  const int wg = (bid & 7) * (NB2 / 8) + (bid >> 3);   // bijective XCD swizzle
  const int m0 = (wg / TILES_N) * BM;
  const int n0 = (wg % TILES_N) * BN;

  const int w = t >> 6;
  const int lane = t & 63;
  const int wm = w >> 2;   // 0..1
  const int wn = w & 3;    // 0..3

  // ---- staging geometry: per K-tile each thread issues 2 A + 2 B gload16.
  // Wave w, load j covers tile-rows [w*32 + j*16, +16), 4 granules (16B) per row.
  // LDS dest linear; source pre-swizzled: granule g = phys ^ ((row>>1)&3).
  const int r0 = w * 32 + (lane >> 2);        // j=0 row-in-tile
  const int r1 = r0 + 16;                     // j=1 row-in-tile
  const int pgs = lane & 3;
  const unsigned aoff0 = (unsigned)(m0 + r0) * K_DIM + (unsigned)(pgs ^ ((r0 >> 1) & 3)) * 8;
  const unsigned aoff1 = (unsigned)(m0 + r1) * K_DIM + (unsigned)(pgs ^ ((r1 >> 1) & 3)) * 8;
  const unsigned boff0 = (unsigned)(n0 + r0) * K_DIM + (unsigned)(pgs ^ ((r0 >> 1) & 3)) * 8;
  const unsigned boff1 = (unsigned)(n0 + r1) * K_DIM + (unsigned)(pgs ^ ((r1 >> 1) & 3)) * 8;
  const int ldst0 = (w * 32) * BK;            // wave-uniform LDS elem offset, j=0
  const int ldst1 = (w * 32 + 16) * BK;       // j=1

  f32x4 acc[8][4];
#pragma unroll
  for (int i = 0; i < 8; ++i)
#pragma unroll
    for (int j = 0; j < 4; ++j) {
      f32x4 z = {0.f, 0.f, 0.f, 0.f};
      acc[i][j] = z;
    }
  bf16x8 Ar0[4], Ar1[4], Br[4];

  const int arow_base = wm * 128 + (lane & 15);
  const int brow_base = wn * 64 + (lane & 15);
  const int kgr = lane >> 4;                  // logical granule for fragments

#define STAGE_A(pre, kt3)                                                     \
  do {                                                                        \
    gload16(A + aoff0 + (unsigned)(kt3) * BK, &sA[pre][ldst0]);               \
    gload16(A + aoff1 + (unsigned)(kt3) * BK, &sA[pre][ldst1]);               \
  } while (0)
#define STAGE_B(pre, kt3)                                                     \
  do {                                                                        \
    gload16(B + boff0 + (unsigned)(kt3) * BK, &sB[pre][ldst0]);               \
    gload16(B + boff1 + (unsigned)(kt3) * BK, &sB[pre][ldst1]);               \
  } while (0)

#define READ_AFR(dst, cur, mib)                                               \
  _Pragma("unroll") for (int i = 0; i < 4; ++i) {                             \
    const int row = arow_base + ((mib) + i) * 16;                             \
    const int pg = kgr ^ ((row >> 1) & 3);                                    \
    dst[i] = *(const bf16x8*)&sA[cur][row * BK + pg * 8];                     \
  }
#define READ_BFR(cur)                                                         \
  _Pragma("unroll") for (int j = 0; j < 4; ++j) {                             \
    const int row = brow_base + j * 16;                                       \
    const int pg = kgr ^ ((row >> 1) & 3);                                    \
    Br[j] = *(const bf16x8*)&sB[cur][row * BK + pg * 8];                      \
  }

#define MMA(ar, accb)                                                         \
  __builtin_amdgcn_s_setprio(1);                                              \
  _Pragma("unroll") for (int i = 0; i < 4; ++i)                               \
  _Pragma("unroll") for (int j = 0; j < 4; ++j)                               \
    acc[(accb) + i][j] = __builtin_amdgcn_mfma_f32_16x16x32_bf16(             \
        ar[i], Br[j], acc[(accb) + i][j], 0, 0, 0);                           \
  __builtin_amdgcn_s_setprio(0);

  // prologue: stage tiles 0,1,2 (12 loads), retire tile 0 (keep 8 in flight)
#pragma unroll
  for (int pt = 0; pt < 3; ++pt) { STAGE_A(pt, pt); STAGE_B(pt, pt); }
  VMCNT(8);
  BAR();

  // steady state: one vmcnt(8) per K-tile, 6-phase issue-to-consume slack
  for (int kt = 0; kt < NKT - 3; ++kt) {
    const int cur = kt & 3, pre = (kt + 3) & 3;
    // ph0
    READ_BFR(cur);
    READ_AFR(Ar0, cur, 0);
    STAGE_A(pre, kt + 3);
    BAR();
    MMA(Ar0, 0);
    BAR();
    // ph1
    READ_AFR(Ar1, cur, 4);
    STAGE_B(pre, kt + 3);
    BAR();
    MMA(Ar1, 4);
    VMCNT(8);                 // retire tile kt+1's 4 loads; 8 stay in flight
    BAR();
  }
  // tail tiles NKT-3, NKT-2, NKT-1: no staging, drain 8 -> 4 -> 0
  {
    const int cur = (NKT - 3) & 3;
    READ_BFR(cur); READ_AFR(Ar0, cur, 0);
    BAR(); MMA(Ar0, 0); BAR();
    READ_AFR(Ar1, cur, 4);
    BAR(); MMA(Ar1, 4);
    VMCNT(4); BAR();
  }
  {
    const int cur = (NKT - 2) & 3;
    READ_BFR(cur); READ_AFR(Ar0, cur, 0);
    BAR(); MMA(Ar0, 0); BAR();
    READ_AFR(Ar1, cur, 4);
    BAR(); MMA(Ar1, 4);
    VMCNT(0); BAR();
  }
  {
    const int cur = (NKT - 1) & 3;
    READ_BFR(cur); READ_AFR(Ar0, cur, 0);
    BAR(); MMA(Ar0, 0); BAR();
    READ_AFR(Ar1, cur, 4);
    BAR(); MMA(Ar1, 4);
  }

  // epilogue: C col = lane&15, row = (lane>>4)*4 + r
  const int colb = n0 + wn * 64 + (lane & 15);
  const int rowb = m0 + wm * 128 + ((lane >> 4) << 2);
#pragma unroll
  for (int j = 0; j < 4; ++j) {
    const int col = colb + j * 16;
    const float bv = bias[col];
#pragma unroll
    for (int ai = 0; ai < 8; ++ai) {
      const int row = rowb + ai * 16;
#pragma unroll
      for (int r = 0; r < 4; ++r)
        out[(size_t)(row + r) * N_DIM + col] = acc[ai][j][r] + bv;
    }
  }
#undef STAGE_A
#undef STAGE_B
#undef READ_AFR
#undef READ_BFR
#undef MMA
}

// ================= fallback: 128x128 inline-dequant GEMM =================
#define FBM 128
#define FBN 128
#define FBK 64
#define FNT_N 86
#define FNT_M 64
#define FNB (FNT_N * FNT_M)

__global__ __launch_bounds__(256, 2) void gemm_fb_kernel(
    const float* __restrict__ Ain, const int* __restrict__ Wcodes,
    const float* __restrict__ scales, const float* __restrict__ bias,
    float* __restrict__ out) {
  __shared__ unsigned short lsA[FBM * FBK];
  __shared__ unsigned short lsB[FBN * FBK];

  const int t = threadIdx.x;
  const int bid = blockIdx.x;
  const int wg = (bid & 7) * (FNB / 8) + (bid >> 3);
  const int m0 = (wg / FNT_N) * FBM;
  const int n0 = (wg % FNT_N) * FBN;

  const int w = t >> 6;
  const int lane = t & 63;
  const int wm = w >> 1, wn = w & 1;
  const int srow = t >> 3;
  const int sp = t & 7;
  const int skc = sp ^ (srow & 7);

  f32x4 acc[4][4];
#pragma unroll
  for (int i = 0; i < 4; ++i)
#pragma unroll
    for (int j = 0; j < 4; ++j) {
      f32x4 z = {0.f, 0.f, 0.f, 0.f};
      acc[i][j] = z;
    }

  for (int kt = 0; kt < K_DIM / FBK; ++kt) {
    const int kg = kt * FBK + skc * 8;
#pragma unroll
    for (int c = 0; c < 4; ++c) {
      const int arow = m0 + c * 32 + srow;
      const float* ap = Ain + (size_t)arow * K_DIM + kg;
      float4 a0 = *(const float4*)ap;
      float4 a1 = *(const float4*)(ap + 4);
      uint4 va;
      va.x = pk2(a0.x, a0.y); va.y = pk2(a0.z, a0.w);
      va.z = pk2(a1.x, a1.y); va.w = pk2(a1.z, a1.w);
      *(uint4*)&lsA[(c * 32 + srow) * FBK + sp * 8] = va;

      const int nrow = n0 + c * 32 + srow;
      const float s = scales[nrow * NGROUPS + (kg >> 7)];
      const int4* wp = (const int4*)(Wcodes + (size_t)nrow * K_DIM + kg);
      int4 c0 = wp[0], c1 = wp[1];
      uint4 vb;
      vb.x = pk2((float)c0.x * s, (float)c0.y * s);
      vb.y = pk2((float)c0.z * s, (float)c0.w * s);
      vb.z = pk2((float)c1.x * s, (float)c1.y * s);
      vb.w = pk2((float)c1.z * s, (float)c1.w * s);
      *(uint4*)&lsB[(c * 32 + srow) * FBK + sp * 8] = vb;
    }
    __syncthreads();
#pragma unroll
    for (int kk = 0; kk < 2; ++kk) {
      bf16x8 af[4], bfr[4];
#pragma unroll
      for (int i = 0; i < 4; ++i) {
        const int row = wm * 64 + i * 16 + (lane & 15);
        const int pg = (kk * 4 + (lane >> 4)) ^ (row & 7);
        af[i] = *(const bf16x8*)&lsA[row * FBK + pg * 8];
      }
#pragma unroll
      for (int j = 0; j < 4; ++j) {
        const int row = wn * 64 + j * 16 + (lane & 15);
        const int pg = (kk * 4 + (lane >> 4)) ^ (row & 7);
        bfr[j] = *(const bf16x8*)&lsB[row * FBK + pg * 8];
      }
#pragma unroll
      for (int i = 0; i < 4; ++i)
#pragma unroll
        for (int j = 0; j < 4; ++j)
          acc[i][j] = __builtin_amdgcn_mfma_f32_16x16x32_bf16(af[i], bfr[j], acc[i][j], 0, 0, 0);
    }
    __syncthreads();
  }

  const int colb = n0 + wn * 64 + (lane & 15);
  const int rowb = m0 + wm * 64 + ((lane >> 4) << 2);
#pragma unroll
  for (int j = 0; j < 4; ++j) {
    const int col = colb + j * 16;
    const float bv = bias[col];
#pragma unroll
    for (int i = 0; i < 4; ++i) {
      const int row = rowb + i * 16;
#pragma unroll
      for (int r = 0; r < 4; ++r)
        out[(size_t)(row + r) * N_DIM + col] = acc[i][j][r] + bv;
    }
  }
}

extern "C" void kernel_launch(void* const* d_in, const int* in_sizes, int n_in,
                              void* d_out, int out_size, void* d_ws, size_t ws_size,
                              hipStream_t stream) {
  const float* Ain = (const float*)d_in[0];
  const int* Wc = (const int*)d_in[1];
  const float* sc = (const float*)d_in[2];
  const float* bias = (const float*)d_in[3];
  float* out = (float*)d_out;

  const size_t needA = (size_t)M_DIM * K_DIM * 2;
  const size_t needB = (size_t)N_DIM * K_DIM * 2;
  if (ws_size >= needA + needB) {
    unsigned short* wsA = (unsigned short*)d_ws;
    unsigned short* wsB = (unsigned short*)((char*)d_ws + needA);
    cvtA_kernel<<<(unsigned)((size_t)M_DIM * K_DIM / 8 / 256), 256, 0, stream>>>(Ain, wsA);
    dequantW_kernel<<<(unsigned)((size_t)N_DIM * K_DIM / 8 / 256), 256, 0, stream>>>(Wc, sc, wsB);
    gemm8_kernel<<<NB2, 512, 0, stream>>>(wsA, wsB, bias, out);
  } else {
    gemm_fb_kernel<<<FNB, 256, 0, stream>>>(Ain, Wc, sc, bias, out);
  }
}

// Round 4
// 959.452 us; speedup vs baseline: 1.0778x; 1.0778x over previous
//
#include <hip/hip_runtime.h>
#include <hip/hip_bf16.h>
#include <cstdint>

#define M_DIM 8192
#define K_DIM 4096
#define N_DIM 11008
#define NGROUPS 32

typedef __attribute__((ext_vector_type(4))) float f32x4;
typedef __attribute__((ext_vector_type(8))) __bf16 bf16x8;

__device__ __forceinline__ unsigned int f2bf(float f) {
  unsigned int u = __builtin_bit_cast(unsigned int, f);
  return (u + 0x7FFFu + ((u >> 16) & 1u)) >> 16;   // RNE f32->bf16
}
__device__ __forceinline__ unsigned int pk2(float lo, float hi) {
  return f2bf(lo) | (f2bf(hi) << 16);
}

// ---------------- prepass: A fp32 -> bf16 ----------------
__global__ __launch_bounds__(256) void cvtA_kernel(const float* __restrict__ in,
                                                   unsigned short* __restrict__ outA) {
  size_t g = (size_t)blockIdx.x * 256 + threadIdx.x;
  size_t base = g * 8;
  const float4* p = (const float4*)(in + base);
  float4 a = p[0], b = p[1];
  uint4 v;
  v.x = pk2(a.x, a.y); v.y = pk2(a.z, a.w);
  v.z = pk2(b.x, b.y); v.w = pk2(b.z, b.w);
  *(uint4*)(outA + base) = v;
}

// ---------------- prepass: W int codes * scale -> bf16 ----------------
__global__ __launch_bounds__(256) void dequantW_kernel(const int* __restrict__ w,
                                                       const float* __restrict__ sc,
                                                       unsigned short* __restrict__ outB) {
  size_t g = (size_t)blockIdx.x * 256 + threadIdx.x;
  size_t base = g * 8;
  unsigned n = (unsigned)(base >> 12);
  unsigned k = (unsigned)base & 4095u;
  float s = sc[n * NGROUPS + (k >> 7)];
  const int4* p = (const int4*)(w + base);
  int4 c0 = p[0], c1 = p[1];
  uint4 v;
  v.x = pk2((float)c0.x * s, (float)c0.y * s);
  v.y = pk2((float)c0.z * s, (float)c0.w * s);
  v.z = pk2((float)c1.x * s, (float)c1.y * s);
  v.w = pk2((float)c1.z * s, (float)c1.w * s);
  *(uint4*)(outB + base) = v;
}

__device__ __forceinline__ void gload16(const void* g, void* l) {
  __builtin_amdgcn_global_load_lds((const __attribute__((address_space(1))) void*)g,
                                   (__attribute__((address_space(3))) void*)l,
                                   16, 0, 0);
}

// ====== 256x256 BK=64 GEMM, read-ahead phases (T1..T5, m201-aligned) ======
#define BM 256
#define BN 256
#define BK 64
#define NKT (K_DIM / BK)          /* 64 */
#define TILES_M (M_DIM / BM)      /* 32 */
#define TILES_N (N_DIM / BN)      /* 43 */
#define NB2 (TILES_M * TILES_N)   /* 1376, %8==0 */

#define VMCNT_(n) asm volatile("s_waitcnt vmcnt(" #n ")" ::: "memory")
#define VMCNT(n) VMCNT_(n)
#define BAR()                                   \
  do {                                          \
    asm volatile("" ::: "memory");              \
    __builtin_amdgcn_s_barrier();               \
    asm volatile("" ::: "memory");              \
  } while (0)
#define SCHEDB() __builtin_amdgcn_sched_barrier(0)

__global__ __launch_bounds__(512, 2) void gemm8_kernel(
    const unsigned short* __restrict__ A,   // bf16 [M][K]
    const unsigned short* __restrict__ B,   // bf16 [N][K]
    const float* __restrict__ bias,
    float* __restrict__ out) {
  __shared__ unsigned short sA[2][BM * BK];
  __shared__ unsigned short sB[2][BN * BK];

  const int t = threadIdx.x;
  const int bid = blockIdx.x;
  const int wg = (bid & 7) * (NB2 / 8) + (bid >> 3);   // bijective XCD swizzle
  const int m0 = (wg / TILES_N) * BM;
  const int n0 = (wg % TILES_N) * BN;

  const int w = t >> 6;
  const int lane = t & 63;
  const int wm = w >> 2;   // 0..1
  const int wn = w & 3;    // 0..3

  // staging geometry (identical to round 2): per K-tile 4 A + 4 B gload16/thread
  //   A pair0 (l=0,1): rows quad0 {0..63}u{128..191};  pair1 (l=2,3): quad1
  //   B pair0 (l=0,1): rows {64h+0..31} (quad0 cols);  pair1 (l=2,3): +32 (quad1)
  const int lr = lane >> 3;            // row within 8-row block
  const int gsw = (lane & 7) ^ lr;     // pre-swizzled logical granule (rule #21)
  int rowA[4], rowB[4];
  unsigned offA[4], offB[4];
#pragma unroll
  for (int l = 0; l < 4; ++l) {
    const int idx = (w << 1) | (l & 1);        // 0..15
    const int bq = (l >> 1) * 64;
    rowA[l] = (idx < 8) ? (bq + idx * 8) : (128 + bq + (idx - 8) * 8);
    rowB[l] = (idx >> 2) * 64 + (l >> 1) * 32 + (idx & 3) * 8;
    offA[l] = (unsigned)(m0 + rowA[l] + lr) * K_DIM + gsw * 8;
    offB[l] = (unsigned)(n0 + rowB[l] + lr) * K_DIM + gsw * 8;
  }

  f32x4 acc[8][4];
#pragma unroll
  for (int i = 0; i < 8; ++i)
#pragma unroll
    for (int j = 0; j < 4; ++j) {
      f32x4 z = {0.f, 0.f, 0.f, 0.f};
      acc[i][j] = z;
    }
  bf16x8 Ar[4][2];        // current A-quad (rotates q0 -> q1 -> next q0)
  bf16x8 B0r[2][2];       // B-quad0 (resident whole tile)
  bf16x8 B1r[2][2];       // B-quad1

  const int arow_base = wm * 128 + (lane & 15);
  const int brow_base = wn * 64 + (lane & 15);
  const int kgr = lane >> 4;

#define STAGE_A2(buf, kt1, p)                                                  \
  do {                                                                         \
    gload16(A + offA[2 * (p)] + (unsigned)(kt1) * BK, &sA[buf][rowA[2 * (p)] * BK]); \
    gload16(A + offA[2 * (p) + 1] + (unsigned)(kt1) * BK, &sA[buf][rowA[2 * (p) + 1] * BK]); \
  } while (0)
#define STAGE_B2(buf, kt1, p)                                                  \
  do {                                                                         \
    gload16(B + offB[2 * (p)] + (unsigned)(kt1) * BK, &sB[buf][rowB[2 * (p)] * BK]); \
    gload16(B + offB[2 * (p) + 1] + (unsigned)(kt1) * BK, &sB[buf][rowB[2 * (p) + 1] * BK]); \
  } while (0)

#define READ_A(buf, qi)                                                        \
  _Pragma("unroll") for (int i = 0; i < 4; ++i) {                              \
    const int row = arow_base + (qi) * 64 + i * 16;                            \
    _Pragma("unroll") for (int kk = 0; kk < 2; ++kk) {                         \
      const int pg = (kk * 4 + kgr) ^ (row & 7);                               \
      Ar[i][kk] = *(const bf16x8*)&sA[buf][row * BK + pg * 8];                 \
    }                                                                          \
  }
#define READ_BQ(dst, buf, qj)                                                  \
  _Pragma("unroll") for (int jj = 0; jj < 2; ++jj) {                           \
    const int row = brow_base + ((qj) * 2 + jj) * 16;                          \
    _Pragma("unroll") for (int kk = 0; kk < 2; ++kk) {                         \
      const int pg = (kk * 4 + kgr) ^ (row & 7);                               \
      dst[jj][kk] = *(const bf16x8*)&sB[buf][row * BK + pg * 8];               \
    }                                                                          \
  }

#define MMA_Q(qi, qj, Bset)                                                    \
  __builtin_amdgcn_s_setprio(1);                                               \
  _Pragma("unroll") for (int kk = 0; kk < 2; ++kk)                             \
  _Pragma("unroll") for (int i = 0; i < 4; ++i)                                \
  _Pragma("unroll") for (int jj = 0; jj < 2; ++jj)                             \
    acc[(qi) * 4 + i][(qj) * 2 + jj] = __builtin_amdgcn_mfma_f32_16x16x32_bf16(\
        Ar[i][kk], Bset[jj][kk], acc[(qi) * 4 + i][(qj) * 2 + jj], 0, 0, 0);   \
  __builtin_amdgcn_s_setprio(0);

  // ---- prologue: stage tile 0 (order B0,A0,B1,A1), drain, preload frags
  STAGE_B2(0, 0, 0); STAGE_A2(0, 0, 0); STAGE_B2(0, 0, 1); STAGE_A2(0, 0, 1);
  VMCNT(0);
  BAR();
  READ_A(0, 0);           // Aq0(t0)
  READ_BQ(B0r, 0, 0);     // Bq0(t0)

  // ---- steady state: reads lead consumption by >=1 phase; 3 counted waits/tile
  for (int kt = 0; kt < NKT - 1; ++kt) {
    const int cur = kt & 1, nxt = cur ^ 1;
    const int k1 = kt + 1;
    // ph0: MMA q(0,0)=A(q0)*B0
    READ_BQ(B1r, cur, 1);         // Bq1(cur), used ph1/ph2
    STAGE_B2(nxt, k1, 0);         // B0-pair of kt+1
    BAR();
    MMA_Q(0, 0, B0r);
    BAR();
    // ph1: MMA q(0,1)=A(q0)*B1; then rotate A -> q1
    STAGE_A2(nxt, k1, 0);         // A0-pair
    VMCNT(4);                     // retires A1-pair(kt): Aq1(cur) data ready
    BAR();
    MMA_Q(0, 1, B1r);
    SCHEDB();
    READ_A(cur, 1);               // Aq1(cur), used ph2/ph3
    BAR();
    // ph2: MMA q(1,1)=A(q1)*B1
    STAGE_B2(nxt, k1, 1);         // B1-pair
    BAR();
    MMA_Q(1, 1, B1r);
    BAR();
    // ph3: MMA q(1,0)=A(q1)*B0; then cross-tile preload
    STAGE_A2(nxt, k1, 1);         // A1-pair
    VMCNT(4);                     // retires B0-pair,A0-pair(kt+1)
    BAR();
    MMA_Q(1, 0, B0r);
    SCHEDB();
    READ_A(nxt, 0);               // Aq0(kt+1)
    READ_BQ(B0r, nxt, 0);         // Bq0(kt+1)
    VMCNT(2);                     // retires B1-pair(kt+1) for next ph0
    BAR();
  }
  // ---- last tile (cur = 1): no staging; drain remaining A1-pair
  {
    READ_BQ(B1r, 1, 1);
    BAR();
    MMA_Q(0, 0, B0r);
    BAR();
    VMCNT(0);                     // retires A1-pair(last)
    BAR();
    MMA_Q(0, 1, B1r);
    SCHEDB();
    READ_A(1, 1);
    BAR();
    BAR();
    MMA_Q(1, 1, B1r);
    BAR();
    BAR();
    MMA_Q(1, 0, B0r);
  }

  // epilogue: C col = lane&15, row = (lane>>4)*4 + r
  const int colb = n0 + wn * 64 + (lane & 15);
  const int rowb = m0 + wm * 128 + ((lane >> 4) << 2);
#pragma unroll
  for (int j = 0; j < 4; ++j) {
    const int col = colb + j * 16;
    const float bv = bias[col];
#pragma unroll
    for (int ai = 0; ai < 8; ++ai) {
      const int row = rowb + ai * 16;
#pragma unroll
      for (int r = 0; r < 4; ++r)
        out[(size_t)(row + r) * N_DIM + col] = acc[ai][j][r] + bv;
    }
  }
#undef STAGE_A2
#undef STAGE_B2
#undef READ_A
#undef READ_BQ
#undef MMA_Q
}

// ================= fallback: 128x128 inline-dequant GEMM =================
#define FBM 128
#define FBN 128
#define FBK 64
#define FNT_N 86
#define FNT_M 64
#define FNB (FNT_N * FNT_M)

__global__ __launch_bounds__(256, 2) void gemm_fb_kernel(
    const float* __restrict__ Ain, const int* __restrict__ Wcodes,
    const float* __restrict__ scales, const float* __restrict__ bias,
    float* __restrict__ out) {
  __shared__ unsigned short lsA[FBM * FBK];
  __shared__ unsigned short lsB[FBN * FBK];

  const int t = threadIdx.x;
  const int bid = blockIdx.x;
  const int wg = (bid & 7) * (FNB / 8) + (bid >> 3);
  const int m0 = (wg / FNT_N) * FBM;
  const int n0 = (wg % FNT_N) * FBN;

  const int w = t >> 6;
  const int lane = t & 63;
  const int wm = w >> 1, wn = w & 1;
  const int srow = t >> 3;
  const int sp = t & 7;
  const int skc = sp ^ (srow & 7);

  f32x4 acc[4][4];
#pragma unroll
  for (int i = 0; i < 4; ++i)
#pragma unroll
    for (int j = 0; j < 4; ++j) {
      f32x4 z = {0.f, 0.f, 0.f, 0.f};
      acc[i][j] = z;
    }

  for (int kt = 0; kt < K_DIM / FBK; ++kt) {
    const int kg = kt * FBK + skc * 8;
#pragma unroll
    for (int c = 0; c < 4; ++c) {
      const int arow = m0 + c * 32 + srow;
      const float* ap = Ain + (size_t)arow * K_DIM + kg;
      float4 a0 = *(const float4*)ap;
      float4 a1 = *(const float4*)(ap + 4);
      uint4 va;
      va.x = pk2(a0.x, a0.y); va.y = pk2(a0.z, a0.w);
      va.z = pk2(a1.x, a1.y); va.w = pk2(a1.z, a1.w);
      *(uint4*)&lsA[(c * 32 + srow) * FBK + sp * 8] = va;

      const int nrow = n0 + c * 32 + srow;
      const float s = scales[nrow * NGROUPS + (kg >> 7)];
      const int4* wp = (const int4*)(Wcodes + (size_t)nrow * K_DIM + kg);
      int4 c0 = wp[0], c1 = wp[1];
      uint4 vb;
      vb.x = pk2((float)c0.x * s, (float)c0.y * s);
      vb.y = pk2((float)c0.z * s, (float)c0.w * s);
      vb.z = pk2((float)c1.x * s, (float)c1.y * s);
      vb.w = pk2((float)c1.z * s, (float)c1.w * s);
      *(uint4*)&lsB[(c * 32 + srow) * FBK + sp * 8] = vb;
    }
    __syncthreads();
#pragma unroll
    for (int kk = 0; kk < 2; ++kk) {
      bf16x8 af[4], bfr[4];
#pragma unroll
      for (int i = 0; i < 4; ++i) {
        const int row = wm * 64 + i * 16 + (lane & 15);
        const int pg = (kk * 4 + (lane >> 4)) ^ (row & 7);
        af[i] = *(const bf16x8*)&lsA[row * FBK + pg * 8];
      }
#pragma unroll
      for (int j = 0; j < 4; ++j) {
        const int row = wn * 64 + j * 16 + (lane & 15);
        const int pg = (kk * 4 + (lane >> 4)) ^ (row & 7);
        bfr[j] = *(const bf16x8*)&lsB[row * FBK + pg * 8];
      }
#pragma unroll
      for (int i = 0; i < 4; ++i)
#pragma unroll
        for (int j = 0; j < 4; ++j)
          acc[i][j] = __builtin_amdgcn_mfma_f32_16x16x32_bf16(af[i], bfr[j], acc[i][j], 0, 0, 0);
    }
    __syncthreads();
  }

  const int colb = n0 + wn * 64 + (lane & 15);
  const int rowb = m0 + wm * 64 + ((lane >> 4) << 2);
#pragma unroll
  for (int j = 0; j < 4; ++j) {
    const int col = colb + j * 16;
    const float bv = bias[col];
#pragma unroll
    for (int i = 0; i < 4; ++i) {
      const int row = rowb + i * 16;
#pragma unroll
      for (int r = 0; r < 4; ++r)
        out[(size_t)(row + r) * N_DIM + col] = acc[i][j][r] + bv;
    }
  }
}

extern "C" void kernel_launch(void* const* d_in, const int* in_sizes, int n_in,
                              void* d_out, int out_size, void* d_ws, size_t ws_size,
                              hipStream_t stream) {
  const float* Ain = (const float*)d_in[0];
  const int* Wc = (const int*)d_in[1];
  const float* sc = (const float*)d_in[2];
  const float* bias = (const float*)d_in[3];
  float* out = (float*)d_out;

  const size_t needA = (size_t)M_DIM * K_DIM * 2;
  const size_t needB = (size_t)N_DIM * K_DIM * 2;
  if (ws_size >= needA + needB) {
    unsigned short* wsA = (unsigned short*)d_ws;
    unsigned short* wsB = (unsigned short*)((char*)d_ws + needA);
    cvtA_kernel<<<(unsigned)((size_t)M_DIM * K_DIM / 8 / 256), 256, 0, stream>>>(Ain, wsA);
    dequantW_kernel<<<(unsigned)((size_t)N_DIM * K_DIM / 8 / 256), 256, 0, stream>>>(Wc, sc, wsB);
    gemm8_kernel<<<NB2, 512, 0, stream>>>(wsA, wsB, bias, out);
  } else {
    gemm_fb_kernel<<<FNB, 256, 0, stream>>>(Ain, Wc, sc, bias, out);
  }
}

// Round 5
// 951.555 us; speedup vs baseline: 1.0868x; 1.0083x over previous
//
#include <hip/hip_runtime.h>
#include <hip/hip_bf16.h>
#include <cstdint>

#define M_DIM 8192
#define K_DIM 4096
#define N_DIM 11008
#define NGROUPS 32

typedef __attribute__((ext_vector_type(4))) float f32x4;
typedef __attribute__((ext_vector_type(8))) __bf16 bf16x8;

__device__ __forceinline__ unsigned int f2bf(float f) {
  unsigned int u = __builtin_bit_cast(unsigned int, f);
  return (u + 0x7FFFu + ((u >> 16) & 1u)) >> 16;   // RNE f32->bf16
}
__device__ __forceinline__ unsigned int pk2(float lo, float hi) {
  return f2bf(lo) | (f2bf(hi) << 16);
}

// ---------------- prepass: A fp32 -> bf16 ----------------
__global__ __launch_bounds__(256) void cvtA_kernel(const float* __restrict__ in,
                                                   unsigned short* __restrict__ outA) {
  size_t g = (size_t)blockIdx.x * 256 + threadIdx.x;
  size_t base = g * 8;
  const float4* p = (const float4*)(in + base);
  float4 a = p[0], b = p[1];
  uint4 v;
  v.x = pk2(a.x, a.y); v.y = pk2(a.z, a.w);
  v.z = pk2(b.x, b.y); v.w = pk2(b.z, b.w);
  *(uint4*)(outA + base) = v;
}

// ---------------- prepass: W int codes * scale -> bf16 ----------------
__global__ __launch_bounds__(256) void dequantW_kernel(const int* __restrict__ w,
                                                       const float* __restrict__ sc,
                                                       unsigned short* __restrict__ outB) {
  size_t g = (size_t)blockIdx.x * 256 + threadIdx.x;
  size_t base = g * 8;
  unsigned n = (unsigned)(base >> 12);
  unsigned k = (unsigned)base & 4095u;
  float s = sc[n * NGROUPS + (k >> 7)];
  const int4* p = (const int4*)(w + base);
  int4 c0 = p[0], c1 = p[1];
  uint4 v;
  v.x = pk2((float)c0.x * s, (float)c0.y * s);
  v.y = pk2((float)c0.z * s, (float)c0.w * s);
  v.z = pk2((float)c1.x * s, (float)c1.y * s);
  v.w = pk2((float)c1.z * s, (float)c1.w * s);
  *(uint4*)(outB + base) = v;
}

__device__ __forceinline__ void gload16(const void* g, void* l) {
  __builtin_amdgcn_global_load_lds((const __attribute__((address_space(1))) void*)g,
                                   (__attribute__((address_space(3))) void*)l,
                                   16, 0, 0);
}

// === 256x256 BK=64 GEMM, m201-faithful deep half-tile pipeline (T1..T5) ===
#define BM 256
#define BN 256
#define BK 64
#define NKT (K_DIM / BK)          /* 64 tiles */
#define TILES_M (M_DIM / BM)      /* 32 */
#define TILES_N (N_DIM / BN)      /* 43 */
#define NB2 (TILES_M * TILES_N)   /* 1376, %8==0 */

#define VMCNT_(n) asm volatile("s_waitcnt vmcnt(" #n ")" ::: "memory")
#define VMCNT(n) VMCNT_(n)
#define LGKM_(n) asm volatile("s_waitcnt lgkmcnt(" #n ")" ::: "memory")
#define LGKM(n) LGKM_(n)
#define BAR()                                   \
  do {                                          \
    asm volatile("" ::: "memory");              \
    __builtin_amdgcn_s_barrier();               \
    asm volatile("" ::: "memory");              \
  } while (0)
#define SCHEDB() __builtin_amdgcn_sched_barrier(0)

__global__ __launch_bounds__(512, 2) void gemm8_kernel(
    const unsigned short* __restrict__ A,   // bf16 [M][K]
    const unsigned short* __restrict__ B,   // bf16 [N][K]
    const float* __restrict__ bias,
    float* __restrict__ out) {
  __shared__ unsigned short sA[2][BM * BK];
  __shared__ unsigned short sB[2][BN * BK];

  const int t = threadIdx.x;
  const int bid = blockIdx.x;
  const int wg = (bid & 7) * (NB2 / 8) + (bid >> 3);   // bijective XCD swizzle
  const int m0 = (wg / TILES_N) * BM;
  const int n0 = (wg % TILES_N) * BN;

  const int w = t >> 6;
  const int lane = t & 63;
  const int wm = w >> 2;   // 0..1
  const int wn = w & 3;    // 0..3

  // staging pairs == quadrant-death regions:
  //   A pair0: rows {0..63}u{128..191} (both wm-groups' q0)   A pair1: q1 rows
  //   B pair0: rows {64h+0..31} (qj=0 cols)                   B pair1: +32 (qj=1)
  const int lr = lane >> 3;
  const int gsw = (lane & 7) ^ lr;     // pre-swizzled source granule (rule #21)
  int rowA[4], rowB[4];
  unsigned offA[4], offB[4];
#pragma unroll
  for (int l = 0; l < 4; ++l) {
    const int idx = (w << 1) | (l & 1);        // 0..15
    const int bq = (l >> 1) * 64;
    rowA[l] = (idx < 8) ? (bq + idx * 8) : (128 + bq + (idx - 8) * 8);
    rowB[l] = (idx >> 2) * 64 + (l >> 1) * 32 + (idx & 3) * 8;
    offA[l] = (unsigned)(m0 + rowA[l] + lr) * K_DIM + gsw * 8;
    offB[l] = (unsigned)(n0 + rowB[l] + lr) * K_DIM + gsw * 8;
  }

  f32x4 acc[8][4];
#pragma unroll
  for (int i = 0; i < 8; ++i)
#pragma unroll
    for (int j = 0; j < 4; ++j) {
      f32x4 z = {0.f, 0.f, 0.f, 0.f};
      acc[i][j] = z;
    }
  bf16x8 Ar[4][2];        // current A-quad fragments
  bf16x8 B0r[2][2];       // B-quad0 (resident across phases 0-3 of a tile)
  bf16x8 B1r[2][2];       // B-quad1

  const int arow_base = wm * 128 + (lane & 15);
  const int brow_base = wn * 64 + (lane & 15);
  const int kgr = lane >> 4;

#define STAGE_A2(buf, kt1, p)                                                  \
  do {                                                                         \
    gload16(A + offA[2 * (p)] + (unsigned)(kt1) * BK, &sA[buf][rowA[2 * (p)] * BK]); \
    gload16(A + offA[2 * (p) + 1] + (unsigned)(kt1) * BK, &sA[buf][rowA[2 * (p) + 1] * BK]); \
  } while (0)
#define STAGE_B2(buf, kt1, p)                                                  \
  do {                                                                         \
    gload16(B + offB[2 * (p)] + (unsigned)(kt1) * BK, &sB[buf][rowB[2 * (p)] * BK]); \
    gload16(B + offB[2 * (p) + 1] + (unsigned)(kt1) * BK, &sB[buf][rowB[2 * (p) + 1] * BK]); \
  } while (0)

#define READ_A(buf, qi)                                                        \
  _Pragma("unroll") for (int i = 0; i < 4; ++i) {                              \
    const int row = arow_base + (qi) * 64 + i * 16;                            \
    _Pragma("unroll") for (int kk = 0; kk < 2; ++kk) {                         \
      const int pg = (kk * 4 + kgr) ^ (row & 7);                               \
      Ar[i][kk] = *(const bf16x8*)&sA[buf][row * BK + pg * 8];                 \
    }                                                                          \
  }
#define READ_BQ(dst, buf, qj)                                                  \
  _Pragma("unroll") for (int jj = 0; jj < 2; ++jj) {                           \
    const int row = brow_base + ((qj) * 2 + jj) * 16;                          \
    _Pragma("unroll") for (int kk = 0; kk < 2; ++kk) {                         \
      const int pg = (kk * 4 + kgr) ^ (row & 7);                               \
      dst[jj][kk] = *(const bf16x8*)&sB[buf][row * BK + pg * 8];               \
    }                                                                          \
  }

#define MMA_Q(qi, qj, Bset)                                                    \
  __builtin_amdgcn_s_setprio(1);                                               \
  _Pragma("unroll") for (int kk = 0; kk < 2; ++kk)                             \
  _Pragma("unroll") for (int i = 0; i < 4; ++i)                                \
  _Pragma("unroll") for (int jj = 0; jj < 2; ++jj)                             \
    acc[(qi) * 4 + i][(qj) * 2 + jj] = __builtin_amdgcn_mfma_f32_16x16x32_bf16(\
        Ar[i][kk], Bset[jj][kk], acc[(qi) * 4 + i][(qj) * 2 + jj], 0, 0, 0);   \
  __builtin_amdgcn_s_setprio(0);

  // ---- prologue: T0 fully (8 loads) + T1 A0,B0,B1 (6 loads); retire T0 only
  STAGE_A2(0, 0, 0); STAGE_B2(0, 0, 0); STAGE_B2(0, 0, 1); STAGE_A2(0, 0, 1);
  STAGE_A2(1, 1, 0); STAGE_B2(1, 1, 0); STAGE_B2(1, 1, 1);
  VMCNT(6);
  BAR();

  // ---- steady state: 8 phases / 2 K-tiles; 1 stage-pair per phase;
  //      two VMCNT(6) per iteration; every load gets >=3.5 phases of slack.
  for (int it = 0; it < 31; ++it) {
    const int t1 = 2 * it + 1, t2 = 2 * it + 2, t3 = 2 * it + 3;
    // ph0: quadrant (0,0) of T(2it) [buf0]
    READ_A(0, 0); READ_BQ(B0r, 0, 0);
    STAGE_A2(1, t1, 1);           // T1.A1 -> buf1 (region died prev ph6)
    LGKM(8);
    BAR();
    LGKM(0); SCHEDB();
    MMA_Q(0, 0, B0r);
    BAR();
    // ph1: (0,1)
    READ_BQ(B1r, 0, 1);
    STAGE_A2(0, t2, 0);           // T2.A0 (died ph0)
    BAR();
    LGKM(0); SCHEDB();
    MMA_Q(0, 1, B1r);
    BAR();
    // ph2: (1,0)
    READ_A(0, 1);
    STAGE_B2(0, t2, 0);           // T2.B0 (died ph0)
    BAR();
    LGKM(0); SCHEDB();
    MMA_Q(1, 0, B0r);
    BAR();
    // ph3: (1,1)
    STAGE_B2(0, t2, 1);           // T2.B1 (died ph1)
    BAR();
    SCHEDB();
    MMA_Q(1, 1, B1r);
    VMCNT(6);                     // retires all of T(2it+1); leaves T2.A0,B0,B1
    BAR();
    // ph4: (0,0) of T(2it+1) [buf1]
    READ_A(1, 0); READ_BQ(B0r, 1, 0);
    STAGE_A2(0, t2, 1);           // T2.A1 (died ph2)
    LGKM(8);
    BAR();
    LGKM(0); SCHEDB();
    MMA_Q(0, 0, B0r);
    BAR();
    // ph5: (0,1)
    READ_BQ(B1r, 1, 1);
    STAGE_A2(1, t3, 0);           // T3.A0 (died ph4)
    BAR();
    LGKM(0); SCHEDB();
    MMA_Q(0, 1, B1r);
    BAR();
    // ph6: (1,0)
    READ_A(1, 1);
    STAGE_B2(1, t3, 0);           // T3.B0 (died ph4)
    BAR();
    LGKM(0); SCHEDB();
    MMA_Q(1, 0, B0r);
    BAR();
    // ph7: (1,1)
    STAGE_B2(1, t3, 1);           // T3.B1 (died ph5)
    BAR();
    SCHEDB();
    MMA_Q(1, 1, B1r);
    VMCNT(6);                     // retires all of T(2it+2); leaves T3.A0,B0,B1
    BAR();
  }

  // ---- epilogue: tiles 62 (buf0), 63 (buf1)
  {
    // ph0
    READ_A(0, 0); READ_BQ(B0r, 0, 0);
    STAGE_A2(1, 63, 1);           // T63.A1
    LGKM(8);
    BAR();
    LGKM(0); SCHEDB();
    MMA_Q(0, 0, B0r);
    BAR();
    // ph1
    READ_BQ(B1r, 0, 1);
    BAR();
    LGKM(0); SCHEDB();
    MMA_Q(0, 1, B1r);
    BAR();
    // ph2
    READ_A(0, 1);
    BAR();
    LGKM(0); SCHEDB();
    MMA_Q(1, 0, B0r);
    BAR();
    // ph3
    BAR();
    SCHEDB();
    MMA_Q(1, 1, B1r);
    VMCNT(0);                     // T63 fully landed
    BAR();
    // ph4
    READ_A(1, 0); READ_BQ(B0r, 1, 0);
    LGKM(8);
    BAR();
    LGKM(0); SCHEDB();
    MMA_Q(0, 0, B0r);
    BAR();
    // ph5
    READ_BQ(B1r, 1, 1);
    BAR();
    LGKM(0); SCHEDB();
    MMA_Q(0, 1, B1r);
    BAR();
    // ph6
    READ_A(1, 1);
    BAR();
    LGKM(0); SCHEDB();
    MMA_Q(1, 0, B0r);
    BAR();
    // ph7
    SCHEDB();
    MMA_Q(1, 1, B1r);
  }

  // epilogue: C col = lane&15, row = (lane>>4)*4 + r
  const int colb = n0 + wn * 64 + (lane & 15);
  const int rowb = m0 + wm * 128 + ((lane >> 4) << 2);
#pragma unroll
  for (int j = 0; j < 4; ++j) {
    const int col = colb + j * 16;
    const float bv = bias[col];
#pragma unroll
    for (int ai = 0; ai < 8; ++ai) {
      const int row = rowb + ai * 16;
#pragma unroll
      for (int r = 0; r < 4; ++r)
        out[(size_t)(row + r) * N_DIM + col] = acc[ai][j][r] + bv;
    }
  }
#undef STAGE_A2
#undef STAGE_B2
#undef READ_A
#undef READ_BQ
#undef MMA_Q
}

// ================= fallback: 128x128 inline-dequant GEMM =================
#define FBM 128
#define FBN 128
#define FBK 64
#define FNT_N 86
#define FNT_M 64
#define FNB (FNT_N * FNT_M)

__global__ __launch_bounds__(256, 2) void gemm_fb_kernel(
    const float* __restrict__ Ain, const int* __restrict__ Wcodes,
    const float* __restrict__ scales, const float* __restrict__ bias,
    float* __restrict__ out) {
  __shared__ unsigned short lsA[FBM * FBK];
  __shared__ unsigned short lsB[FBN * FBK];

  const int t = threadIdx.x;
  const int bid = blockIdx.x;
  const int wg = (bid & 7) * (FNB / 8) + (bid >> 3);
  const int m0 = (wg / FNT_N) * FBM;
  const int n0 = (wg % FNT_N) * FBN;

  const int w = t >> 6;
  const int lane = t & 63;
  const int wm = w >> 1, wn = w & 1;
  const int srow = t >> 3;
  const int sp = t & 7;
  const int skc = sp ^ (srow & 7);

  f32x4 acc[4][4];
#pragma unroll
  for (int i = 0; i < 4; ++i)
#pragma unroll
    for (int j = 0; j < 4; ++j) {
      f32x4 z = {0.f, 0.f, 0.f, 0.f};
      acc[i][j] = z;
    }

  for (int kt = 0; kt < K_DIM / FBK; ++kt) {
    const int kg = kt * FBK + skc * 8;
#pragma unroll
    for (int c = 0; c < 4; ++c) {
      const int arow = m0 + c * 32 + srow;
      const float* ap = Ain + (size_t)arow * K_DIM + kg;
      float4 a0 = *(const float4*)ap;
      float4 a1 = *(const float4*)(ap + 4);
      uint4 va;
      va.x = pk2(a0.x, a0.y); va.y = pk2(a0.z, a0.w);
      va.z = pk2(a1.x, a1.y); va.w = pk2(a1.z, a1.w);
      *(uint4*)&lsA[(c * 32 + srow) * FBK + sp * 8] = va;

      const int nrow = n0 + c * 32 + srow;
      const float s = scales[nrow * NGROUPS + (kg >> 7)];
      const int4* wp = (const int4*)(Wcodes + (size_t)nrow * K_DIM + kg);
      int4 c0 = wp[0], c1 = wp[1];
      uint4 vb;
      vb.x = pk2((float)c0.x * s, (float)c0.y * s);
      vb.y = pk2((float)c0.z * s, (float)c0.w * s);
      vb.z = pk2((float)c1.x * s, (float)c1.y * s);
      vb.w = pk2((float)c1.z * s, (float)c1.w * s);
      *(uint4*)&lsB[(c * 32 + srow) * FBK + sp * 8] = vb;
    }
    __syncthreads();
#pragma unroll
    for (int kk = 0; kk < 2; ++kk) {
      bf16x8 af[4], bfr[4];
#pragma unroll
      for (int i = 0; i < 4; ++i) {
        const int row = wm * 64 + i * 16 + (lane & 15);
        const int pg = (kk * 4 + (lane >> 4)) ^ (row & 7);
        af[i] = *(const bf16x8*)&lsA[row * FBK + pg * 8];
      }
#pragma unroll
      for (int j = 0; j < 4; ++j) {
        const int row = wn * 64 + j * 16 + (lane & 15);
        const int pg = (kk * 4 + (lane >> 4)) ^ (row & 7);
        bfr[j] = *(const bf16x8*)&lsB[row * FBK + pg * 8];
      }
#pragma unroll
      for (int i = 0; i < 4; ++i)
#pragma unroll
        for (int j = 0; j < 4; ++j)
          acc[i][j] = __builtin_amdgcn_mfma_f32_16x16x32_bf16(af[i], bfr[j], acc[i][j], 0, 0, 0);
    }
    __syncthreads();
  }

  const int colb = n0 + wn * 64 + (lane & 15);
  const int rowb = m0 + wm * 64 + ((lane >> 4) << 2);
#pragma unroll
  for (int j = 0; j < 4; ++j) {
    const int col = colb + j * 16;
    const float bv = bias[col];
#pragma unroll
    for (int i = 0; i < 4; ++i) {
      const int row = rowb + i * 16;
#pragma unroll
      for (int r = 0; r < 4; ++r)
        out[(size_t)(row + r) * N_DIM + col] = acc[i][j][r] + bv;
    }
  }
}

extern "C" void kernel_launch(void* const* d_in, const int* in_sizes, int n_in,
                              void* d_out, int out_size, void* d_ws, size_t ws_size,
                              hipStream_t stream) {
  const float* Ain = (const float*)d_in[0];
  const int* Wc = (const int*)d_in[1];
  const float* sc = (const float*)d_in[2];
  const float* bias = (const float*)d_in[3];
  float* out = (float*)d_out;

  const size_t needA = (size_t)M_DIM * K_DIM * 2;
  const size_t needB = (size_t)N_DIM * K_DIM * 2;
  if (ws_size >= needA + needB) {
    unsigned short* wsA = (unsigned short*)d_ws;
    unsigned short* wsB = (unsigned short*)((char*)d_ws + needA);
    cvtA_kernel<<<(unsigned)((size_t)M_DIM * K_DIM / 8 / 256), 256, 0, stream>>>(Ain, wsA);
    dequantW_kernel<<<(unsigned)((size_t)N_DIM * K_DIM / 8 / 256), 256, 0, stream>>>(Wc, sc, wsB);
    gemm8_kernel<<<NB2, 512, 0, stream>>>(wsA, wsB, bias, out);
  } else {
    gemm_fb_kernel<<<FNB, 256, 0, stream>>>(Ain, Wc, sc, bias, out);
  }
}

// Round 6
// 880.115 us; speedup vs baseline: 1.1750x; 1.0812x over previous
//
#include <hip/hip_runtime.h>
#include <hip/hip_bf16.h>
#include <cstdint>

#define M_DIM 8192
#define K_DIM 4096
#define N_DIM 11008
#define NGROUPS 32

typedef __attribute__((ext_vector_type(4))) float f32x4;
typedef __attribute__((ext_vector_type(8))) __bf16 bf16x8;

__device__ __forceinline__ unsigned int f2bf(float f) {
  unsigned int u = __builtin_bit_cast(unsigned int, f);
  return (u + 0x7FFFu + ((u >> 16) & 1u)) >> 16;   // RNE f32->bf16
}
__device__ __forceinline__ unsigned int pk2(float lo, float hi) {
  return f2bf(lo) | (f2bf(hi) << 16);
}

// ---------------- prepass: A fp32 -> bf16 ----------------
__global__ __launch_bounds__(256) void cvtA_kernel(const float* __restrict__ in,
                                                   unsigned short* __restrict__ outA) {
  size_t g = (size_t)blockIdx.x * 256 + threadIdx.x;
  size_t base = g * 8;
  const float4* p = (const float4*)(in + base);
  float4 a = p[0], b = p[1];
  uint4 v;
  v.x = pk2(a.x, a.y); v.y = pk2(a.z, a.w);
  v.z = pk2(b.x, b.y); v.w = pk2(b.z, b.w);
  *(uint4*)(outA + base) = v;
}

// ---------------- prepass: W int codes * scale -> bf16 ----------------
__global__ __launch_bounds__(256) void dequantW_kernel(const int* __restrict__ w,
                                                       const float* __restrict__ sc,
                                                       unsigned short* __restrict__ outB) {
  size_t g = (size_t)blockIdx.x * 256 + threadIdx.x;
  size_t base = g * 8;
  unsigned n = (unsigned)(base >> 12);
  unsigned k = (unsigned)base & 4095u;
  float s = sc[n * NGROUPS + (k >> 7)];
  const int4* p = (const int4*)(w + base);
  int4 c0 = p[0], c1 = p[1];
  uint4 v;
  v.x = pk2((float)c0.x * s, (float)c0.y * s);
  v.y = pk2((float)c0.z * s, (float)c0.w * s);
  v.z = pk2((float)c1.x * s, (float)c1.y * s);
  v.w = pk2((float)c1.z * s, (float)c1.w * s);
  *(uint4*)(outB + base) = v;
}

__device__ __forceinline__ void gload16(const void* g, void* l) {
  __builtin_amdgcn_global_load_lds((const __attribute__((address_space(1))) void*)g,
                                   (__attribute__((address_space(3))) void*)l,
                                   16, 0, 0);
}

// === 256x256, BK=32, 4-deep buffers, register read-ahead, 1 barrier/phase ===
#define BM 256
#define BN 256
#define BK 32
#define NKT (K_DIM / BK)          /* 128 */
#define TILES_M (M_DIM / BM)      /* 32 */
#define TILES_N (N_DIM / BN)      /* 43 */
#define NB2 (TILES_M * TILES_N)   /* 1376, %8==0 */
#define TSZ (BM * BK)             /* 16 KiB per buffer */

#define VMCNT_(n) asm volatile("s_waitcnt vmcnt(" #n ")" ::: "memory")
#define VMCNT(n) VMCNT_(n)
#define BAR()                                   \
  do {                                          \
    asm volatile("" ::: "memory");              \
    __builtin_amdgcn_s_barrier();               \
    asm volatile("" ::: "memory");              \
  } while (0)

__global__ __launch_bounds__(512, 2) void gemm8_kernel(
    const unsigned short* __restrict__ A,   // bf16 [M][K]
    const unsigned short* __restrict__ B,   // bf16 [N][K]
    const float* __restrict__ bias,
    float* __restrict__ out) {
  __shared__ unsigned short sA[4][TSZ];   // 64 KiB
  __shared__ unsigned short sB[4][TSZ];   // 64 KiB

  const int t = threadIdx.x;
  const int bid = blockIdx.x;
  const int wg = (bid & 7) * (NB2 / 8) + (bid >> 3);   // bijective XCD swizzle
  const int m0 = (wg / TILES_N) * BM;
  const int n0 = (wg % TILES_N) * BN;

  const int w = t >> 6;
  const int lane = t & 63;
  const int wm = w >> 2;   // 0..1
  const int wn = w & 3;    // 0..3

  // staging (identical to round 2): per K-tile 2 A-instr + 2 B-instr per thread
  const int r0 = w * 32 + (lane >> 2);
  const int r1 = r0 + 16;
  const int pgs = lane & 3;
  const unsigned aoff0 = (unsigned)(m0 + r0) * K_DIM + (unsigned)(pgs ^ ((r0 >> 1) & 3)) * 8;
  const unsigned aoff1 = (unsigned)(m0 + r1) * K_DIM + (unsigned)(pgs ^ ((r1 >> 1) & 3)) * 8;
  const unsigned boff0 = (unsigned)(n0 + r0) * K_DIM + (unsigned)(pgs ^ ((r0 >> 1) & 3)) * 8;
  const unsigned boff1 = (unsigned)(n0 + r1) * K_DIM + (unsigned)(pgs ^ ((r1 >> 1) & 3)) * 8;
  const int ldst0 = (w * 32) * BK;
  const int ldst1 = (w * 32 + 16) * BK;

  f32x4 acc[8][4];
#pragma unroll
  for (int i = 0; i < 8; ++i)
#pragma unroll
    for (int j = 0; j < 4; ++j) {
      f32x4 z = {0.f, 0.f, 0.f, 0.f};
      acc[i][j] = z;
    }
  // double frag sets (a/b), static indexing only
  bf16x8 Ar0a[4], Ar1a[4], Bra[4];
  bf16x8 Ar0b[4], Ar1b[4], Brb[4];

  const int arow_base = wm * 128 + (lane & 15);
  const int brow_base = wn * 64 + (lane & 15);
  const int kgr = lane >> 4;

#define STAGE_A2(buf, kt)                                                     \
  do {                                                                        \
    gload16(A + aoff0 + (unsigned)(kt) * BK, &sA[buf][ldst0]);                \
    gload16(A + aoff1 + (unsigned)(kt) * BK, &sA[buf][ldst1]);                \
  } while (0)
#define STAGE_B2(buf, kt)                                                     \
  do {                                                                        \
    gload16(B + boff0 + (unsigned)(kt) * BK, &sB[buf][ldst0]);                \
    gload16(B + boff1 + (unsigned)(kt) * BK, &sB[buf][ldst1]);                \
  } while (0)

#define READ_AQ(dst, buf, mib)                                                \
  _Pragma("unroll") for (int i = 0; i < 4; ++i) {                             \
    const int row = arow_base + ((mib) + i) * 16;                             \
    const int pg = kgr ^ ((row >> 1) & 3);                                    \
    dst[i] = *(const bf16x8*)&sA[buf][row * BK + pg * 8];                     \
  }
#define READ_BQ(dst, buf)                                                     \
  _Pragma("unroll") for (int j = 0; j < 4; ++j) {                             \
    const int row = brow_base + j * 16;                                       \
    const int pg = kgr ^ ((row >> 1) & 3);                                    \
    dst[j] = *(const bf16x8*)&sB[buf][row * BK + pg * 8];                     \
  }

#define MMA(ar, br, accb)                                                     \
  __builtin_amdgcn_s_setprio(1);                                              \
  _Pragma("unroll") for (int i = 0; i < 4; ++i)                               \
  _Pragma("unroll") for (int j = 0; j < 4; ++j)                               \
    acc[(accb) + i][j] = __builtin_amdgcn_mfma_f32_16x16x32_bf16(             \
        ar[i], br[j], acc[(accb) + i][j], 0, 0, 0);                           \
  __builtin_amdgcn_s_setprio(0);

  // ph(kt,A): read own quad1 (next phase's A), stage (kt+3).A, MMA quad0, vmcnt, bar
#define PH_A(CB, SB, KT3, A0, A1, BR, VN)                                     \
  READ_AQ(A1, CB, 4);                                                         \
  STAGE_A2(SB, KT3);                                                          \
  MMA(A0, BR, 0);                                                             \
  VMCNT(VN);                                                                  \
  BAR();
#define PH_A_NS(CB, A0, A1, BR, VN)                                           \
  READ_AQ(A1, CB, 4);                                                         \
  MMA(A0, BR, 0);                                                             \
  VMCNT(VN);                                                                  \
  BAR();
  // ph(kt,B): read NEXT tile's quad0+B, stage (kt+3).B, MMA quad1, bar
#define PH_B(NB, SB, KT3, A1, BR, NA0, NBR)                                   \
  READ_AQ(NA0, NB, 0);                                                        \
  READ_BQ(NBR, NB);                                                           \
  STAGE_B2(SB, KT3);                                                          \
  MMA(A1, BR, 4);                                                             \
  BAR();
#define PH_B_NS(NB, A1, BR, NA0, NBR)                                         \
  READ_AQ(NA0, NB, 0);                                                        \
  READ_BQ(NBR, NB);                                                           \
  MMA(A1, BR, 4);                                                             \
  BAR();

  // ---- prologue: stage tiles 0,1,2 fully (12 instr); retire tile 0; preload set a
  STAGE_A2(0, 0); STAGE_B2(0, 0);
  STAGE_A2(1, 1); STAGE_B2(1, 1);
  STAGE_A2(2, 2); STAGE_B2(2, 2);
  VMCNT(6);
  BAR();
  READ_AQ(Ar0a, 0, 0);
  READ_BQ(Bra, 0);

  // ---- main: 31 iters x 4 tiles (tiles 0..123); buffers/sets compile-time
  for (int it = 0; it < 31; ++it) {
    const int k3 = 4 * it + 3, k4 = 4 * it + 4, k5 = 4 * it + 5, k6 = 4 * it + 6;
    PH_A(0, 3, k3, Ar0a, Ar1a, Bra, 6)
    PH_B(1, 3, k3, Ar1a, Bra, Ar0b, Brb)
    PH_A(1, 0, k4, Ar0b, Ar1b, Brb, 6)
    PH_B(2, 0, k4, Ar1b, Brb, Ar0a, Bra)
    PH_A(2, 1, k5, Ar0a, Ar1a, Bra, 6)
    PH_B(3, 1, k5, Ar1a, Bra, Ar0b, Brb)
    PH_A(3, 2, k6, Ar0b, Ar1b, Brb, 6)
    PH_B(0, 2, k6, Ar1b, Brb, Ar0a, Bra)
  }

  // ---- peel tiles 124..127 (bufs 0,1,2,3; sets a,b,a,b); drain 6->4->0
  PH_A(0, 3, 127, Ar0a, Ar1a, Bra, 6)
  PH_B(1, 3, 127, Ar1a, Bra, Ar0b, Brb)
  PH_A_NS(1, Ar0b, Ar1b, Brb, 4)
  PH_B_NS(2, Ar1b, Brb, Ar0a, Bra)
  PH_A_NS(2, Ar0a, Ar1a, Bra, 0)
  PH_B_NS(3, Ar1a, Bra, Ar0b, Brb)
  // tile 127: no further reads/stages/waits
  READ_AQ(Ar1b, 3, 4);
  MMA(Ar0b, Brb, 0);
  MMA(Ar1b, Brb, 4);

  // C epilogue: col = lane&15, row = (lane>>4)*4 + r
  const int colb = n0 + wn * 64 + (lane & 15);
  const int rowb = m0 + wm * 128 + ((lane >> 4) << 2);
#pragma unroll
  for (int j = 0; j < 4; ++j) {
    const int col = colb + j * 16;
    const float bv = bias[col];
#pragma unroll
    for (int ai = 0; ai < 8; ++ai) {
      const int row = rowb + ai * 16;
#pragma unroll
      for (int r = 0; r < 4; ++r)
        out[(size_t)(row + r) * N_DIM + col] = acc[ai][j][r] + bv;
    }
  }
#undef STAGE_A2
#undef STAGE_B2
#undef READ_AQ
#undef READ_BQ
#undef MMA
#undef PH_A
#undef PH_B
#undef PH_A_NS
#undef PH_B_NS
}

// ================= fallback: 128x128 inline-dequant GEMM =================
#define FBM 128
#define FBN 128
#define FBK 64
#define FNT_N 86
#define FNT_M 64
#define FNB (FNT_N * FNT_M)

__global__ __launch_bounds__(256, 2) void gemm_fb_kernel(
    const float* __restrict__ Ain, const int* __restrict__ Wcodes,
    const float* __restrict__ scales, const float* __restrict__ bias,
    float* __restrict__ out) {
  __shared__ unsigned short lsA[FBM * FBK];
  __shared__ unsigned short lsB[FBN * FBK];

  const int t = threadIdx.x;
  const int bid = blockIdx.x;
  const int wg = (bid & 7) * (FNB / 8) + (bid >> 3);
  const int m0 = (wg / FNT_N) * FBM;
  const int n0 = (wg % FNT_N) * FBN;

  const int w = t >> 6;
  const int lane = t & 63;
  const int wm = w >> 1, wn = w & 1;
  const int srow = t >> 3;
  const int sp = t & 7;
  const int skc = sp ^ (srow & 7);

  f32x4 acc[4][4];
#pragma unroll
  for (int i = 0; i < 4; ++i)
#pragma unroll
    for (int j = 0; j < 4; ++j) {
      f32x4 z = {0.f, 0.f, 0.f, 0.f};
      acc[i][j] = z;
    }

  for (int kt = 0; kt < K_DIM / FBK; ++kt) {
    const int kg = kt * FBK + skc * 8;
#pragma unroll
    for (int c = 0; c < 4; ++c) {
      const int arow = m0 + c * 32 + srow;
      const float* ap = Ain + (size_t)arow * K_DIM + kg;
      float4 a0 = *(const float4*)ap;
      float4 a1 = *(const float4*)(ap + 4);
      uint4 va;
      va.x = pk2(a0.x, a0.y); va.y = pk2(a0.z, a0.w);
      va.z = pk2(a1.x, a1.y); va.w = pk2(a1.z, a1.w);
      *(uint4*)&lsA[(c * 32 + srow) * FBK + sp * 8] = va;

      const int nrow = n0 + c * 32 + srow;
      const float s = scales[nrow * NGROUPS + (kg >> 7)];
      const int4* wp = (const int4*)(Wcodes + (size_t)nrow * K_DIM + kg);
      int4 c0 = wp[0], c1 = wp[1];
      uint4 vb;
      vb.x = pk2((float)c0.x * s, (float)c0.y * s);
      vb.y = pk2((float)c0.z * s, (float)c0.w * s);
      vb.z = pk2((float)c1.x * s, (float)c1.y * s);
      vb.w = pk2((float)c1.z * s, (float)c1.w * s);
      *(uint4*)&lsB[(c * 32 + srow) * FBK + sp * 8] = vb;
    }
    __syncthreads();
#pragma unroll
    for (int kk = 0; kk < 2; ++kk) {
      bf16x8 af[4], bfr[4];
#pragma unroll
      for (int i = 0; i < 4; ++i) {
        const int row = wm * 64 + i * 16 + (lane & 15);
        const int pg = (kk * 4 + (lane >> 4)) ^ (row & 7);
        af[i] = *(const bf16x8*)&lsA[row * FBK + pg * 8];
      }
#pragma unroll
      for (int j = 0; j < 4; ++j) {
        const int row = wn * 64 + j * 16 + (lane & 15);
        const int pg = (kk * 4 + (lane >> 4)) ^ (row & 7);
        bfr[j] = *(const bf16x8*)&lsB[row * FBK + pg * 8];
      }
#pragma unroll
      for (int i = 0; i < 4; ++i)
#pragma unroll
        for (int j = 0; j < 4; ++j)
          acc[i][j] = __builtin_amdgcn_mfma_f32_16x16x32_bf16(af[i], bfr[j], acc[i][j], 0, 0, 0);
    }
    __syncthreads();
  }

  const int colb = n0 + wn * 64 + (lane & 15);
  const int rowb = m0 + wm * 64 + ((lane >> 4) << 2);
#pragma unroll
  for (int j = 0; j < 4; ++j) {
    const int col = colb + j * 16;
    const float bv = bias[col];
#pragma unroll
    for (int i = 0; i < 4; ++i) {
      const int row = rowb + i * 16;
#pragma unroll
      for (int r = 0; r < 4; ++r)
        out[(size_t)(row + r) * N_DIM + col] = acc[i][j][r] + bv;
    }
  }
}

extern "C" void kernel_launch(void* const* d_in, const int* in_sizes, int n_in,
                              void* d_out, int out_size, void* d_ws, size_t ws_size,
                              hipStream_t stream) {
  const float* Ain = (const float*)d_in[0];
  const int* Wc = (const int*)d_in[1];
  const float* sc = (const float*)d_in[2];
  const float* bias = (const float*)d_in[3];
  float* out = (float*)d_out;

  const size_t needA = (size_t)M_DIM * K_DIM * 2;
  const size_t needB = (size_t)N_DIM * K_DIM * 2;
  if (ws_size >= needA + needB) {
    unsigned short* wsA = (unsigned short*)d_ws;
    unsigned short* wsB = (unsigned short*)((char*)d_ws + needA);
    cvtA_kernel<<<(unsigned)((size_t)M_DIM * K_DIM / 8 / 256), 256, 0, stream>>>(Ain, wsA);
    dequantW_kernel<<<(unsigned)((size_t)N_DIM * K_DIM / 8 / 256), 256, 0, stream>>>(Wc, sc, wsB);
    gemm8_kernel<<<NB2, 512, 0, stream>>>(wsA, wsB, bias, out);
  } else {
    gemm_fb_kernel<<<FNB, 256, 0, stream>>>(Ain, Wc, sc, bias, out);
  }
}